// Round 1
// baseline (135.441 us; speedup 1.0000x reference)
//
#include <hip/hip_runtime.h>

// Problem constants (fixed by reference shapes)
#define NB 2        // batch
#define BB 257      // bins
#define PB 256      // centers = bins-1
#define LL 16       // patches per image (4x4)
#define QQ 12544    // points per patch (112*112)
#define KP 112      // patch size
#define WIMG 448    // image width
#define SPLIT 16    // Q-slices per (n,l)
#define QS 784      // QQ / SPLIT (exact)
#define BIGV 1e10f
#define SENT 3e18f  // sentinel for invalid points: (c-SENT)^2 ~ 9e36, finite, loses all mins

// ws layout (floats): [0 .. NB*LL*PB) minY  | [+0 .. NB*LL) sumY | [+NB*LL .. ) cnt
#define WS_MINY 0
#define WS_SUMY (NB*LL*PB)
#define WS_CNT  (NB*LL*PB + NB*LL)
#define WS_TOTAL (NB*LL*PB + 2*NB*LL)

__global__ void init_ws_kernel(float* __restrict__ ws) {
    int i = blockIdx.x * 256 + threadIdx.x;
    if (i < WS_SUMY) ws[i] = BIGV;          // minY init
    else if (i < WS_TOTAL) ws[i] = 0.f;     // sums + counts
}

__global__ __launch_bounds__(256) void chamfer_main(const float* __restrict__ bins,
                                                    const float* __restrict__ img,
                                                    float* __restrict__ ws) {
    __shared__ float cent[PB];
    __shared__ float pts[QS];
    __shared__ float rs[4], rc[4];

    const int bid = blockIdx.x;
    const int s  = bid % SPLIT;
    const int nl = bid / SPLIT;      // 0..NB*LL-1
    const int l  = nl % LL;
    const int n  = nl / LL;
    const int t  = threadIdx.x;

    // --- centers into LDS (bins layout (N,B,L): idx = (n*BB + b)*LL + l) ---
    {
        float b0 = bins[(n*BB + t    )*LL + l];
        float b1 = bins[(n*BB + t + 1)*LL + l];
        cent[t] = 0.5f * (b0 + b1);
    }

    // --- point slice into LDS, masked with sentinel ---
    // patch l: rows (l/4)*112.., cols (l%4)*112..; point q -> pixel (q/112, q%112)
    const float* pimg = img + n*WIMG*WIMG + (l >> 2)*KP*WIMG + (l & 3)*KP;
    const int q0 = s * QS;
    for (int i = t; i < QS; i += 256) {
        int q = q0 + i;
        int ki = q / KP, kj = q % KP;
        float v = pimg[ki*WIMG + kj];
        pts[i] = (v > 0.f) ? v : SENT;
    }
    __syncthreads();

    // --- Pass A: thread t owns center t; min over this slice's points ---
    {
        const float c = cent[t];
        float m = BIGV;
        #pragma unroll 8
        for (int i = 0; i < QS; ++i) {
            float diff = c - pts[i];      // broadcast LDS read (same addr all lanes)
            m = fminf(m, diff * diff);
        }
        // all candidate values >= 0 -> uint ordering == float ordering
        atomicMin((unsigned int*)&ws[WS_MINY + nl*PB + t], __float_as_uint(m));
    }

    // --- Pass B: each thread a strided subset of points; min over 256 centers ---
    float lsum = 0.f, lcnt = 0.f;
    for (int i = t; i < QS; i += 256) {
        float x = pts[i];
        bool valid = (x < 1e17f);
        float dmin = BIGV;
        #pragma unroll 16
        for (int p = 0; p < PB; ++p) {
            float diff = cent[p] - x;
            dmin = fminf(dmin, diff * diff);
        }
        if (valid) { lsum += dmin; lcnt += 1.f; }
    }

    // --- block reduce (4 waves of 64) ---
    for (int off = 32; off; off >>= 1) {
        lsum += __shfl_down(lsum, off);
        lcnt += __shfl_down(lcnt, off);
    }
    const int wid = t >> 6, lane = t & 63;
    if (lane == 0) { rs[wid] = lsum; rc[wid] = lcnt; }
    __syncthreads();
    if (t == 0) {
        float S = rs[0] + rs[1] + rs[2] + rs[3];
        float C = rc[0] + rc[1] + rc[2] + rc[3];
        atomicAdd(&ws[WS_SUMY + nl], S);
        atomicAdd(&ws[WS_CNT  + nl], C);
    }
}

__global__ void chamfer_final(const float* __restrict__ ws, float* __restrict__ out) {
    __shared__ float pp[NB*LL];
    const int t = threadIdx.x;
    const int g = t >> 3, j = t & 7;   // 32 groups of 8 threads; group g = (n,l) pair

    float s = 0.f;
    for (int p = j; p < PB; p += 8) s += ws[WS_MINY + g*PB + p];
    s += __shfl_down(s, 4, 8);
    s += __shfl_down(s, 2, 8);
    s += __shfl_down(s, 1, 8);
    if (j == 0) {
        float cham_x = s * (1.f / PB);
        float sy = ws[WS_SUMY + g];
        float cy = ws[WS_CNT  + g];
        float cham_y = sy / fmaxf(cy, 1.f);
        pp[g] = (cy > 0.f) ? (cham_x + cham_y) : 0.f;
    }
    __syncthreads();
    if (t == 0) {
        float acc = 0.f;
        #pragma unroll
        for (int i = 0; i < NB*LL; ++i) acc += pp[i];
        out[0] = acc * (1.f / (NB*LL));
    }
}

extern "C" void kernel_launch(void* const* d_in, const int* in_sizes, int n_in,
                              void* d_out, int out_size, void* d_ws, size_t ws_size,
                              hipStream_t stream) {
    const float* bins = (const float*)d_in[0];
    const float* img  = (const float*)d_in[1];
    float* ws  = (float*)d_ws;
    float* out = (float*)d_out;

    int init_blocks = (WS_TOTAL + 255) / 256;
    hipLaunchKernelGGL(init_ws_kernel, dim3(init_blocks), dim3(256), 0, stream, ws);
    hipLaunchKernelGGL(chamfer_main, dim3(NB*LL*SPLIT), dim3(256), 0, stream, bins, img, ws);
    hipLaunchKernelGGL(chamfer_final, dim3(1), dim3(256), 0, stream, ws, out);
}

// Round 2
// 19.643 us; speedup vs baseline: 6.8953x; 6.8953x over previous
//
#include <hip/hip_runtime.h>

// Problem constants (fixed by reference shapes)
#define NB 2        // batch
#define BB 257      // bins
#define PB 256      // centers = bins-1
#define LL 16       // patches per image (4x4)
#define QQ 12544    // points per patch (112*112)
#define KP 112      // patch size
#define WIMG 448    // image width
#define SPLIT 16    // Q-slices per (n,l)
#define QS 784      // QQ / SPLIT (exact)
#define NPATCH (NB*LL)  // 32
#define BIGV 1e10f
#define SENT_LO (-2e18f)
#define SENT_HI ( 2e18f)

// ws layout (4B elements)
#define CS_OFF 0                                   // sorted centers: 32*256 f32
#define LO_OFF (NPATCH*PB)                         // below-candidates: 32*256 u32 (encoded)
#define HI_OFF (2*NPATCH*PB)                       // above-candidates: 32*256 u32 (encoded)
#define SY_OFF (3*NPATCH*PB)                       // per-slice sumY: 32*16 f32
#define CT_OFF (3*NPATCH*PB + NPATCH*SPLIT)        // per-slice count: 32*16 f32

// monotone float<->uint mapping: uint order == float order
__device__ __forceinline__ unsigned encf(float f) {
    unsigned u = __float_as_uint(f);
    return (u >> 31) ? ~u : (u | 0x80000000u);
}
__device__ __forceinline__ float decf(unsigned e) {
    return __uint_as_float((e >> 31) ? (e & 0x7fffffffu) : ~e);
}
__device__ __forceinline__ unsigned umaxu(unsigned a, unsigned b){ return a > b ? a : b; }
__device__ __forceinline__ unsigned uminu(unsigned a, unsigned b){ return a < b ? a : b; }

// ---- kernel 1: per-patch center computation + bitonic sort + ws init ----
__global__ __launch_bounds__(256) void sort_init(const float* __restrict__ bins,
                                                 float* __restrict__ wsf,
                                                 unsigned* __restrict__ wsu) {
    const int g = blockIdx.x;           // patch id 0..31
    const int n = g / LL, l = g % LL;
    const int t = threadIdx.x;
    __shared__ float s[PB];

    float b0 = bins[(n*BB + t    )*LL + l];
    float b1 = bins[(n*BB + t + 1)*LL + l];
    s[t] = 0.5f * (b0 + b1);
    __syncthreads();

    // bitonic sort, ascending
    for (int k = 2; k <= PB; k <<= 1) {
        for (int j = k >> 1; j > 0; j >>= 1) {
            int ixj = t ^ j;
            if (ixj > t) {
                float a = s[t], b = s[ixj];
                bool up = ((t & k) == 0);
                if ((a > b) == up) { s[t] = b; s[ixj] = a; }
            }
            __syncthreads();
        }
    }

    wsf[CS_OFF + g*PB + t] = s[t];
    wsu[LO_OFF + g*PB + t] = encf(SENT_LO);
    wsu[HI_OFF + g*PB + t] = encf(SENT_HI);
}

// ---- kernel 2: per point -> binary search, chamfer y->x sum, lo/hi candidates ----
__global__ __launch_bounds__(256) void chamfer_main(const float* __restrict__ img,
                                                    float* __restrict__ wsf,
                                                    unsigned* __restrict__ wsu) {
    const int bid = blockIdx.x;
    const int sl = bid % SPLIT;
    const int g  = bid / SPLIT;          // patch id
    const int l  = g % LL, n = g / LL;
    const int t  = threadIdx.x;

    __shared__ float cs[PB];
    __shared__ unsigned lop[PB], hih[PB];
    __shared__ float rs[4], rc[4];

    cs[t]  = wsf[CS_OFF + g*PB + t];
    lop[t] = encf(SENT_LO);
    hih[t] = encf(SENT_HI);
    __syncthreads();

    const float* pimg = img + n*WIMG*WIMG + (l >> 2)*KP*WIMG + (l & 3)*KP;
    float ls = 0.f, lc = 0.f;

    for (int i = t; i < QS; i += 256) {
        int q = sl*QS + i;
        int ki = q / KP, kj = q - ki*KP;
        float v = pimg[ki*WIMG + kj];
        if (v > 0.f) {
            // branchless lower_bound over 256 sorted centers
            int u = 0;
            #pragma unroll
            for (int stp = 128; stp; stp >>= 1)
                u += (cs[u + stp - 1] < v) ? stp : 0;
            u += (cs[PB-1] < v) ? 1 : 0;   // allow u == 256 when v > all centers

            float dmin = BIGV;
            if (u > 0) {
                float d = v - cs[u-1];
                dmin = d*d;
                atomicMin(&hih[u-1], encf(v));   // v is an above-candidate for center u-1
            }
            if (u < PB) {
                float d = cs[u] - v;
                dmin = fminf(dmin, d*d);
                atomicMax(&lop[u], encf(v));     // v is a below-candidate for center u
            }
            ls += dmin;
            lc += 1.f;
        }
    }

    // block reduce sums (deterministic per slice; stored as plain partials)
    for (int m = 32; m; m >>= 1) { ls += __shfl_xor(ls, m); lc += __shfl_xor(lc, m); }
    const int wid = t >> 6, lane = t & 63;
    if (lane == 0) { rs[wid] = ls; rc[wid] = lc; }
    __syncthreads();
    if (t == 0) {
        wsf[SY_OFF + g*SPLIT + sl] = rs[0]+rs[1]+rs[2]+rs[3];
        wsf[CT_OFF + g*SPLIT + sl] = rc[0]+rc[1]+rc[2]+rc[3];
    }

    // merge candidates to global (order-independent atomics -> deterministic)
    unsigned lv = lop[t];
    if (lv != encf(SENT_LO)) atomicMax(&wsu[LO_OFF + g*PB + t], lv);
    unsigned hv = hih[t];
    if (hv != encf(SENT_HI)) atomicMin(&wsu[HI_OFF + g*PB + t], hv);
}

__device__ __forceinline__ float nn_term(float c, unsigned lo, unsigned hi) {
    float a = c - decf(lo);
    float b = decf(hi) - c;
    return fminf(a*a, b*b);
}

// ---- kernel 3: prefix/suffix scans per patch, chamfer x->y, final mean ----
__global__ __launch_bounds__(1024) void chamfer_final(const float* __restrict__ wsf,
                                                      const unsigned* __restrict__ wsu,
                                                      float* __restrict__ out) {
    const int t = threadIdx.x;
    const int w = t >> 6, lane = t & 63;   // 16 waves; wave handles patches w, w+16
    __shared__ float pp[NPATCH];

    for (int g = w; g < NPATCH; g += 16) {
        uint4  lp = reinterpret_cast<const uint4*>(wsu + LO_OFF)[g*64 + lane];
        uint4  hp = reinterpret_cast<const uint4*>(wsu + HI_OFF)[g*64 + lane];
        float4 cv = reinterpret_cast<const float4*>(wsf + CS_OFF)[g*64 + lane];

        // prefix-max (encoded) over 256 slots: serial-4 then wave scan
        unsigned p0 = lp.x, p1 = umaxu(p0, lp.y), p2 = umaxu(p1, lp.z), p3 = umaxu(p2, lp.w);
        unsigned inc = p3;
        for (int d = 1; d < 64; d <<= 1) {
            unsigned o = __shfl_up(inc, d);
            if (lane >= d) inc = umaxu(inc, o);
        }
        unsigned ex = __shfl_up(inc, 1);
        if (lane == 0) ex = encf(SENT_LO);
        unsigned lo0 = umaxu(ex,p0), lo1 = umaxu(ex,p1), lo2 = umaxu(ex,p2), lo3 = umaxu(ex,p3);

        // suffix-min (encoded)
        unsigned s3 = hp.w, s2 = uminu(hp.z, s3), s1 = uminu(hp.y, s2), s0 = uminu(hp.x, s1);
        unsigned incs = s0;
        for (int d = 1; d < 64; d <<= 1) {
            unsigned o = __shfl_down(incs, d);
            if (lane + d < 64) incs = uminu(incs, o);
        }
        unsigned exh = __shfl_down(incs, 1);
        if (lane == 63) exh = encf(SENT_HI);
        unsigned hi0 = uminu(exh,s0), hi1 = uminu(exh,s1), hi2 = uminu(exh,s2), hi3 = uminu(exh,s3);

        float sum = nn_term(cv.x, lo0, hi0) + nn_term(cv.y, lo1, hi1)
                  + nn_term(cv.z, lo2, hi2) + nn_term(cv.w, lo3, hi3);
        for (int m = 32; m; m >>= 1) sum += __shfl_xor(sum, m);

        if (lane == 0) {
            float sy = 0.f, cy = 0.f;
            for (int s2i = 0; s2i < SPLIT; ++s2i) {
                sy += wsf[SY_OFF + g*SPLIT + s2i];
                cy += wsf[CT_OFF + g*SPLIT + s2i];
            }
            float chx = sum * (1.0f / PB);
            float chy = sy / fmaxf(cy, 1.f);
            pp[g] = (cy > 0.5f) ? (chx + chy) : 0.f;
        }
    }
    __syncthreads();
    if (t == 0) {
        float acc = 0.f;
        #pragma unroll
        for (int i = 0; i < NPATCH; ++i) acc += pp[i];
        out[0] = acc * (1.0f / NPATCH);
    }
}

extern "C" void kernel_launch(void* const* d_in, const int* in_sizes, int n_in,
                              void* d_out, int out_size, void* d_ws, size_t ws_size,
                              hipStream_t stream) {
    const float* bins = (const float*)d_in[0];
    const float* img  = (const float*)d_in[1];
    float*    wsf = (float*)d_ws;
    unsigned* wsu = (unsigned*)d_ws;
    float*    out = (float*)d_out;

    hipLaunchKernelGGL(sort_init,    dim3(NPATCH),       dim3(256),  0, stream, bins, wsf, wsu);
    hipLaunchKernelGGL(chamfer_main, dim3(NPATCH*SPLIT), dim3(256),  0, stream, img, wsf, wsu);
    hipLaunchKernelGGL(chamfer_final,dim3(1),            dim3(1024), 0, stream, wsf, wsu, out);
}